// Round 13
// baseline (237.366 us; speedup 1.0000x reference)
//
#include <hip/hip_runtime.h>
#include <math.h>

#define SEQ 4096
#define DIM 1024

typedef _Float16 f16;
typedef _Float16 f16x8 __attribute__((ext_vector_type(8)));
typedef _Float16 f16x4 __attribute__((ext_vector_type(4)));
typedef float f32x4 __attribute__((ext_vector_type(4)));

#define GLOAD_LDS16(g, l)                                              \
    __builtin_amdgcn_global_load_lds(                                  \
        (const __attribute__((address_space(1))) void*)(g),            \
        (__attribute__((address_space(3))) void*)(l), 16, 0, 0)

// ---------------------------------------------------------------------------
// prep: merged input-split and weight-transpose dispatch.
//   bid < 4096 : split role — X row -> (Xh, Xl) fp16 + rowsum sx.
//   else       : wtrans role — W 32x32 tile -> W^T fp16 (wq/wk minus 0.5).
// ---------------------------------------------------------------------------
__global__ __launch_bounds__(256) void prep(
    const float* __restrict__ x,
    const float* __restrict__ Wq, const float* __restrict__ Wk,
    const float* __restrict__ Wv,
    f16* __restrict__ Xh, f16* __restrict__ Xl, float* __restrict__ sx,
    f16* __restrict__ QT, f16* __restrict__ KT, f16* __restrict__ VT) {
    __shared__ float tile[32][33];
    __shared__ float sred[4];
    const int tid = threadIdx.x;
    const int bid = blockIdx.x;

    if (bid < 4096) {
        const int i = bid * 256 + tid;
        const float4 v = ((const float4*)x)[i];
        const float vv[4] = {v.x, v.y, v.z, v.w};
        f16x4 h, l;
#pragma unroll
        for (int q = 0; q < 4; ++q) {
            const f16 hq = (f16)vv[q];
            h[q] = hq;
            l[q] = (f16)(vv[q] - (float)hq);
        }
        ((f16x4*)Xh)[i] = h;
        ((f16x4*)Xl)[i] = l;
        float s = v.x + v.y + v.z + v.w;
#pragma unroll
        for (int m = 32; m >= 1; m >>= 1) s += __shfl_xor(s, m);
        if ((tid & 63) == 0) sred[tid >> 6] = s;
        __syncthreads();
        if (tid == 0) sx[bid] = sred[0] + sred[1] + sred[2] + sred[3];
        return;
    }

    const int w = bid - 4096;
    const int z = w >> 10;
    const int idx = w & 1023;
    const int r0 = (idx >> 5) * 32;
    const int c0 = (idx & 31) * 32;
    const float* W = (z == 0) ? Wq : (z == 1) ? Wk : Wv;
    f16* T = (z == 0) ? QT : (z == 1) ? KT : VT;
    const float off = (z < 2) ? 0.5f : 0.0f;
    {
        const int r = tid >> 3, c = (tid & 7) * 4;
        const float4 v = *(const float4*)&W[(size_t)(r0 + r) * DIM + c0 + c];
        tile[r][c + 0] = v.x;
        tile[r][c + 1] = v.y;
        tile[r][c + 2] = v.z;
        tile[r][c + 3] = v.w;
    }
    __syncthreads();
    {
        const int n = tid >> 3;
        const int k = (tid & 7) * 4;
        f16x4 h;
#pragma unroll
        for (int q = 0; q < 4; ++q) h[q] = (f16)(tile[k + q][n] - off);
        *(f16x4*)&T[(size_t)(c0 + n) * DIM + r0 + k] = h;
    }
}

// ---------------------------------------------------------------------------
// Generalized 128x128 fp16 MFMA GEMM (proven schedule): BK=64, 256 thr,
// double-buffered counted-vmcnt, XOR swizzle, XCD swizzle.  3 sets by by>>3.
// EPI_SPLIT16 additionally: fused per-row sum -> atomicAdd into rs (if set).
// ---------------------------------------------------------------------------
#define EPI_F32 0
#define EPI_SPLIT16 1
#define EPI_TRANS16 2

template <int NPAIR, int KTILES>
__global__ __launch_bounds__(256, 2) void gemm128s(
    const f16* __restrict__ A0, const f16* __restrict__ A1, int ldA, int ldB,
    const f16* __restrict__ B0_0, const f16* __restrict__ B1_0,
    void* o0_0, void* o1_0,
    const f16* __restrict__ B0_1, const f16* __restrict__ B1_1,
    void* o0_1, void* o1_1,
    const f16* __restrict__ B0_2, const f16* __restrict__ B1_2,
    void* o0_2, void* o1_2,
    float* rs0, float* rs1,
    int epi0, int epi1, int epi2,
    int N, float scale) {
    __shared__ __align__(16) f16 As[2][128 * 64];
    __shared__ __align__(16) f16 Bs[2][128 * 64];

    const int tid = threadIdx.x;
    const int lane = tid & 63;
    const int wid = tid >> 6;
    const int wr = wid >> 1, wc = wid & 1;

    const int total = (int)(gridDim.y << 5);
    int lid = (int)blockIdx.y * 32 + (int)blockIdx.x;
    lid = (lid & 7) * (total >> 3) + (lid >> 3);
    const int bx = lid & 31;
    int by = lid >> 5;

    const int set = by >> 3;
    by &= 7;

    const f16 *B0, *B1;
    void *o0, *o1;
    int epi;
    float* rs;
    if (set == 0)      { B0 = B0_0; B1 = B1_0; o0 = o0_0; o1 = o1_0; epi = epi0; rs = rs0; }
    else if (set == 1) { B0 = B0_1; B1 = B1_1; o0 = o0_1; o1 = o1_1; epi = epi1; rs = rs1; }
    else               { B0 = B0_2; B1 = B1_2; o0 = o0_2; o1 = o1_2; epi = epi2; rs = nullptr; }

    const int m0 = bx * 128;
    const int n0 = by * 128;

    const f16* APs[2] = {A0, A1};
    const f16* BPs[2] = {B0, B1};
    const int nt = NPAIR * KTILES;

    f32x4 acc[4][4];
#pragma unroll
    for (int i = 0; i < 4; ++i)
#pragma unroll
        for (int j = 0; j < 4; ++j) acc[i][j] = (f32x4){0.f, 0.f, 0.f, 0.f};

    auto STAGE = [&](int t, int b) {
        const int pass = t / KTILES;
        const int k0 = (t % KTILES) * 64;
        const f16* Ap = APs[pass];
        const f16* Bp = BPs[pass];
#pragma unroll
        for (int L = 0; L < 4; ++L) {
            const int idx = L * 256 + tid;
            const int row = idx >> 3;
            const int sc = ((idx & 7) * 16) ^ ((row & 7) << 4);
            const int ldsu = (L * 256 + (tid & ~63)) * 8;
            GLOAD_LDS16(Ap + (size_t)(m0 + row) * ldA + k0 + (sc >> 1),
                        &As[b][ldsu]);
            GLOAD_LDS16(Bp + (size_t)(n0 + row) * ldB + k0 + (sc >> 1),
                        &Bs[b][ldsu]);
        }
    };

    STAGE(0, 0);

    for (int t = 0; t < nt; ++t) {
        const int cur = t & 1;
        __builtin_amdgcn_s_barrier();
        asm volatile("" ::: "memory");
        if (t + 1 < nt) {
            STAGE(t + 1, cur ^ 1);
            asm volatile("s_waitcnt vmcnt(8)" ::: "memory");
        } else {
            asm volatile("s_waitcnt vmcnt(0)" ::: "memory");
        }
        __builtin_amdgcn_s_barrier();
        asm volatile("" ::: "memory");

#pragma unroll
        for (int kk = 0; kk < 2; ++kk) {
            const int cb = kk * 64 + (lane >> 4) * 16;
            f16x8 af[4], bv[4];
#pragma unroll
            for (int i = 0; i < 4; ++i) {
                const int r = wr * 64 + i * 16 + (lane & 15);
                af[i] = *(const f16x8*)(&As[cur][r * 64 +
                                                 ((cb ^ ((r & 7) << 4)) >> 1)]);
            }
#pragma unroll
            for (int j = 0; j < 4; ++j) {
                const int r = wc * 64 + j * 16 + (lane & 15);
                bv[j] = *(const f16x8*)(&Bs[cur][r * 64 +
                                                 ((cb ^ ((r & 7) << 4)) >> 1)]);
            }
            __builtin_amdgcn_s_setprio(1);
#pragma unroll
            for (int i = 0; i < 4; ++i)
#pragma unroll
                for (int j = 0; j < 4; ++j)
                    acc[i][j] = __builtin_amdgcn_mfma_f32_16x16x32_f16(
                        af[i], bv[j], acc[i][j], 0, 0, 0);
            __builtin_amdgcn_s_setprio(0);
        }
    }

    const int row0 = m0 + wr * 64 + (lane >> 4) * 4;
    const int col0 = n0 + wc * 64 + (lane & 15);

    if (epi == EPI_F32) {
        float* O = (float*)o0;
#pragma unroll
        for (int i = 0; i < 4; ++i)
#pragma unroll
            for (int j = 0; j < 4; ++j)
#pragma unroll
                for (int q = 0; q < 4; ++q)
                    O[(size_t)(row0 + i * 16 + q) * N + col0 + j * 16] =
                        acc[i][j][q] * scale;
    } else if (epi == EPI_SPLIT16) {
        f16* Hi = (f16*)o0;
        f16* Lo = (f16*)o1;
#pragma unroll
        for (int i = 0; i < 4; ++i)
#pragma unroll
            for (int j = 0; j < 4; ++j)
#pragma unroll
                for (int q = 0; q < 4; ++q) {
                    const float x = acc[i][j][q];
                    const f16 h = (f16)x;
                    const size_t idx = (size_t)(row0 + i * 16 + q) * N + col0 + j * 16;
                    Hi[idx] = h;
                    if (Lo) Lo[idx] = (f16)(x - (float)h);
                }
        if (rs) {
#pragma unroll
            for (int i = 0; i < 4; ++i)
#pragma unroll
                for (int q = 0; q < 4; ++q) {
                    float rsum = acc[i][0][q] + acc[i][1][q] +
                                 acc[i][2][q] + acc[i][3][q];
#pragma unroll
                    for (int msk = 1; msk < 16; msk <<= 1)
                        rsum += __shfl_xor(rsum, msk);
                    if ((lane & 15) == 0)
                        atomicAdd(&rs[row0 + i * 16 + q], rsum);
                }
        }
    } else {  // EPI_TRANS16
        f16* OT = (f16*)o0;
#pragma unroll
        for (int i = 0; i < 4; ++i)
#pragma unroll
            for (int j = 0; j < 4; ++j) {
                f16x4 v;
#pragma unroll
                for (int q = 0; q < 4; ++q) v[q] = (f16)acc[i][j][q];
                *(f16x4*)&OT[(size_t)(col0 + j * 16) * SEQ + row0 + i * 16] = v;
            }
    }
}

// ---------------------------------------------------------------------------
// QK~ 256x256 fp16 GEMM + rank-1 epilogue + block-local softmax (round 10).
// ---------------------------------------------------------------------------
template <int NPAIR, int KT>
__global__ __launch_bounds__(512, 2) void qkrank1(
    const f16* __restrict__ A0, const f16* __restrict__ B0,
    const f16* __restrict__ A1, const f16* __restrict__ B1,
    const float* __restrict__ sx, const float* __restrict__ rq,
    const float* __restrict__ rk,
    f16* __restrict__ Pu, float* __restrict__ Mp, float* __restrict__ Lp) {
    constexpr int K = KT * 64;
    constexpr int nt = NPAIR * KT;
    __shared__ __align__(16) f16 As[2][256 * 64];   // 64 KB
    __shared__ __align__(16) f16 Bs[2][256 * 64];   // 64 KB

    const int tid = threadIdx.x;
    const int lane = tid & 63;
    const int wid = tid >> 6;
    const int wr = wid >> 2;
    const int wc = wid & 3;

    const int wg = ((int)blockIdx.x & 7) * 32 + ((int)blockIdx.x >> 3);
    const int m0 = (wg >> 4) * 256;
    const int n0 = (wg & 15) * 256;
    const int bcol = n0 >> 8;

    const f16* APs[2] = {A0, A1};
    const f16* BPs[2] = {B0, B1};

    f32x4 acc[8][4];
#pragma unroll
    for (int i = 0; i < 8; ++i)
#pragma unroll
        for (int j = 0; j < 4; ++j) acc[i][j] = (f32x4){0.f, 0.f, 0.f, 0.f};

    auto STAGE = [&](int t, int b) {
        const f16* Ap = APs[t / KT];
        const f16* Bp = BPs[t / KT];
        const int k0 = (t % KT) * 64;
#pragma unroll
        for (int L = 0; L < 4; ++L) {
            const int idx = L * 512 + tid;
            const int row = idx >> 3;
            const int sc = ((idx & 7) * 16) ^ ((row & 7) << 4);
            const int ldsu = (L * 512 + (tid & ~63)) * 8;
            GLOAD_LDS16(Ap + (size_t)(m0 + row) * K + k0 + (sc >> 1),
                        &As[b][ldsu]);
            GLOAD_LDS16(Bp + (size_t)(n0 + row) * K + k0 + (sc >> 1),
                        &Bs[b][ldsu]);
        }
    };

    STAGE(0, 0);

    for (int t = 0; t < nt; ++t) {
        const int cur = t & 1;
        __builtin_amdgcn_s_barrier();
        asm volatile("" ::: "memory");
        if (t + 1 < nt) {
            STAGE(t + 1, cur ^ 1);
            asm volatile("s_waitcnt vmcnt(8)" ::: "memory");
        } else {
            asm volatile("s_waitcnt vmcnt(0)" ::: "memory");
        }
        __builtin_amdgcn_s_barrier();
        asm volatile("" ::: "memory");

#pragma unroll
        for (int kk = 0; kk < 2; ++kk) {
            const int cb = kk * 64 + (lane >> 4) * 16;
            f16x8 af[8], bv[4];
#pragma unroll
            for (int i = 0; i < 8; ++i) {
                const int r = wr * 128 + i * 16 + (lane & 15);
                af[i] = *(const f16x8*)(&As[cur][r * 64 +
                                                 ((cb ^ ((r & 7) << 4)) >> 1)]);
            }
#pragma unroll
            for (int j = 0; j < 4; ++j) {
                const int r = wc * 64 + j * 16 + (lane & 15);
                bv[j] = *(const f16x8*)(&Bs[cur][r * 64 +
                                                 ((cb ^ ((r & 7) << 4)) >> 1)]);
            }
            __builtin_amdgcn_s_setprio(1);
#pragma unroll
            for (int i = 0; i < 8; ++i)
#pragma unroll
                for (int j = 0; j < 4; ++j)
                    acc[i][j] = __builtin_amdgcn_mfma_f32_16x16x32_f16(
                        af[i], bv[j], acc[i][j], 0, 0, 0);
            __builtin_amdgcn_s_setprio(0);
        }
    }

    // ---- epilogue: rank-1 + scale (in place) ----
    const int g4 = lane >> 4;
    const int l15 = lane & 15;
    const int row0 = m0 + wr * 128 + g4 * 4;
    const int col0 = n0 + wc * 64 + l15;
    float u[4], w4[4];
#pragma unroll
    for (int j = 0; j < 4; ++j) {
        const float sxc = sx[col0 + j * 16];
        u[j] = 256.f * sxc + 0.5f * rk[col0 + j * 16];
        w4[j] = 0.5f * sxc;
    }
#pragma unroll
    for (int i = 0; i < 8; ++i)
#pragma unroll
        for (int q = 0; q < 4; ++q) {
            const int r = row0 + i * 16 + q;
            const float sxr = sx[r];
            const float rqr = rq[r];
#pragma unroll
            for (int j = 0; j < 4; ++j)
                acc[i][j][q] =
                    (acc[i][j][q] + sxr * u[j] + rqr * w4[j]) * 0.03125f;
        }

    // ---- block-local softmax over the 256-col strip ----
    float* partm = (float*)&As[0][0];      // [256][4]
    float* mrow  = partm + 1024;           // [256]
    float* parts = mrow + 256;             // [256][4]
    float red[8][4];
#pragma unroll
    for (int i = 0; i < 8; ++i)
#pragma unroll
        for (int q = 0; q < 4; ++q) {
            float v = acc[i][0][q];
#pragma unroll
            for (int j = 1; j < 4; ++j) v = fmaxf(v, acc[i][j][q]);
            red[i][q] = v;
        }
#pragma unroll
    for (int msk = 1; msk < 16; msk <<= 1)
#pragma unroll
        for (int i = 0; i < 8; ++i)
#pragma unroll
            for (int q = 0; q < 4; ++q)
                red[i][q] = fmaxf(red[i][q], __shfl_xor(red[i][q], msk));
    __syncthreads();
    if (l15 == 0)
#pragma unroll
        for (int i = 0; i < 8; ++i)
#pragma unroll
            for (int q = 0; q < 4; ++q)
                partm[(wr * 128 + i * 16 + g4 * 4 + q) * 4 + wc] = red[i][q];
    __syncthreads();
    if (tid < 256) {
        const float* p = partm + tid * 4;
        mrow[tid] = fmaxf(fmaxf(p[0], p[1]), fmaxf(p[2], p[3]));
    }
    __syncthreads();
#pragma unroll
    for (int i = 0; i < 8; ++i)
#pragma unroll
        for (int q = 0; q < 4; ++q) {
            const float mB = mrow[wr * 128 + i * 16 + g4 * 4 + q];
            float s = 0.f;
#pragma unroll
            for (int j = 0; j < 4; ++j) {
                const float e = __expf(acc[i][j][q] - mB);
                acc[i][j][q] = e;
                s += e;
            }
            red[i][q] = s;
        }
#pragma unroll
    for (int msk = 1; msk < 16; msk <<= 1)
#pragma unroll
        for (int i = 0; i < 8; ++i)
#pragma unroll
            for (int q = 0; q < 4; ++q) red[i][q] += __shfl_xor(red[i][q], msk);
    if (l15 == 0)
#pragma unroll
        for (int i = 0; i < 8; ++i)
#pragma unroll
            for (int q = 0; q < 4; ++q)
                parts[(wr * 128 + i * 16 + g4 * 4 + q) * 4 + wc] = red[i][q];
    __syncthreads();
    if (tid < 256) {
        const float* p = parts + tid * 4;
        Mp[(size_t)(m0 + tid) * 16 + bcol] = mrow[tid];
        Lp[(size_t)(m0 + tid) * 16 + bcol] = p[0] + p[1] + p[2] + p[3];
    }
    // ---- write Pu (f16, unnormalized exp) ----
#pragma unroll
    for (int i = 0; i < 8; ++i)
#pragma unroll
        for (int q = 0; q < 4; ++q) {
            const size_t r = row0 + i * 16 + q;
#pragma unroll
            for (int j = 0; j < 4; ++j)
                Pu[r * SEQ + col0 + j * 16] = (f16)acc[i][j][q];
        }
}

// ---------------------------------------------------------------------------
// PV with folded normalization + in-kernel D: each block computes D for its
// 128 rows x its 8 strips (LDS) from Mp/Lp, then the proven 128x128 schedule
// with a D-fold every 4 BK-tiles.  Output: atomicAdd into pre-zeroed O.
// ---------------------------------------------------------------------------
template <int KTILES>   // tiles per K-half (32)
__global__ __launch_bounds__(256, 2) void pvstrip(
    const f16* __restrict__ Pu, const f16* __restrict__ VT,
    const float* __restrict__ Mp, const float* __restrict__ Lp,
    float* __restrict__ O) {
    __shared__ __align__(16) f16 As[2][128 * 64];
    __shared__ __align__(16) f16 Bs[2][128 * 64];
    __shared__ float Dl[128][8];

    const int tid = threadIdx.x;
    const int lane = tid & 63;
    const int wid = tid >> 6;
    const int wr = wid >> 1, wc = wid & 1;

    const int total = (int)(gridDim.y << 5);
    int lid = (int)blockIdx.y * 32 + (int)blockIdx.x;
    lid = (lid & 7) * (total >> 3) + (lid >> 3);
    const int bx = lid & 31;
    int by = lid >> 5;
    const int set = by >> 3;
    by &= 7;
    const int koff = set * 2048;           // element offset along K
    const int strip0 = set * 8;

    const int m0 = bx * 128;
    const int n0 = by * 128;
    const int row0 = m0 + wr * 64 + (lane >> 4) * 4;
    const int col0 = n0 + wc * 64 + (lane & 15);

    f32x4 acc[4][4], acc2[4][4];
#pragma unroll
    for (int i = 0; i < 4; ++i)
#pragma unroll
        for (int j = 0; j < 4; ++j) {
            acc[i][j] = (f32x4){0.f, 0.f, 0.f, 0.f};
            acc2[i][j] = (f32x4){0.f, 0.f, 0.f, 0.f};
        }

    auto STAGE = [&](int t, int b) {
        const int k0 = t * 64 + koff;
#pragma unroll
        for (int L = 0; L < 4; ++L) {
            const int idx = L * 256 + tid;
            const int row = idx >> 3;
            const int sc = ((idx & 7) * 16) ^ ((row & 7) << 4);
            const int ldsu = (L * 256 + (tid & ~63)) * 8;
            GLOAD_LDS16(Pu + (size_t)(m0 + row) * SEQ + k0 + (sc >> 1),
                        &As[b][ldsu]);
            GLOAD_LDS16(VT + (size_t)(n0 + row) * SEQ + k0 + (sc >> 1),
                        &Bs[b][ldsu]);
        }
    };

    STAGE(0, 0);

    // In-block D: rows m0..m0+127, strips strip0..strip0+7 (overlaps STAGE 0).
    if (tid < 128) {
        const size_t r = m0 + tid;
        float mv[16];
        float m = -1e30f;
#pragma unroll
        for (int b = 0; b < 16; ++b) {
            mv[b] = Mp[r * 16 + b];
            m = fmaxf(m, mv[b]);
        }
        float l = 0.f;
#pragma unroll
        for (int b = 0; b < 16; ++b) l += __expf(mv[b] - m) * Lp[r * 16 + b];
        const float inv = 1.f / l;
#pragma unroll
        for (int s = 0; s < 8; ++s)
            Dl[tid][s] = __expf(mv[strip0 + s] - m) * inv;
    }
    __syncthreads();

    for (int t = 0; t < KTILES; ++t) {
        const int cur = t & 1;
        __builtin_amdgcn_s_barrier();
        asm volatile("" ::: "memory");
        if (t + 1 < KTILES) {
            STAGE(t + 1, cur ^ 1);
            asm volatile("s_waitcnt vmcnt(8)" ::: "memory");
        } else {
            asm volatile("s_waitcnt vmcnt(0)" ::: "memory");
        }
        __builtin_amdgcn_s_barrier();
        asm volatile("" ::: "memory");

#pragma unroll
        for (int kk = 0; kk < 2; ++kk) {
            const int cb = kk * 64 + (lane >> 4) * 16;
            f16x8 af[4], bv[4];
#pragma unroll
            for (int i = 0; i < 4; ++i) {
                const int r = wr * 64 + i * 16 + (lane & 15);
                af[i] = *(const f16x8*)(&As[cur][r * 64 +
                                                 ((cb ^ ((r & 7) << 4)) >> 1)]);
            }
#pragma unroll
            for (int j = 0; j < 4; ++j) {
                const int r = wc * 64 + j * 16 + (lane & 15);
                bv[j] = *(const f16x8*)(&Bs[cur][r * 64 +
                                                 ((cb ^ ((r & 7) << 4)) >> 1)]);
            }
            __builtin_amdgcn_s_setprio(1);
#pragma unroll
            for (int i = 0; i < 4; ++i)
#pragma unroll
                for (int j = 0; j < 4; ++j)
                    acc[i][j] = __builtin_amdgcn_mfma_f32_16x16x32_f16(
                        af[i], bv[j], acc[i][j], 0, 0, 0);
            __builtin_amdgcn_s_setprio(0);
        }

        if ((t & 3) == 3) {   // strip boundary: fold D (LDS) and reset
            const int s = t >> 2;
            const int lr0 = wr * 64 + ((lane >> 4)) * 4;
#pragma unroll
            for (int i = 0; i < 4; ++i)
#pragma unroll
                for (int q = 0; q < 4; ++q) {
                    const float dv = Dl[lr0 + i * 16 + q][s];
#pragma unroll
                    for (int j = 0; j < 4; ++j) {
                        acc2[i][j][q] += dv * acc[i][j][q];
                        acc[i][j][q] = 0.f;
                    }
                }
        }
    }

#pragma unroll
    for (int i = 0; i < 4; ++i)
#pragma unroll
        for (int j = 0; j < 4; ++j)
#pragma unroll
            for (int q = 0; q < 4; ++q)
                atomicAdd(&O[(size_t)(row0 + i * 16 + q) * DIM + col0 + j * 16],
                          acc2[i][j][q]);
}

// ---------------------------------------------------------------------------
extern "C" void kernel_launch(void* const* d_in, const int* in_sizes, int n_in,
                              void* d_out, int out_size, void* d_ws, size_t ws_size,
                              hipStream_t stream) {
    const float* x  = (const float*)d_in[0];
    const float* wq = (const float*)d_in[1];
    const float* wk = (const float*)d_in[2];
    const float* wv = (const float*)d_in[3];
    float* O = (float*)d_out;

    char* ws = (char*)d_ws;
    const size_t MB = 1024 * 1024;
    const size_t KB = 1024;
    f16* Qh = (f16*)(ws + 0 * MB);
    f16* Ql = (f16*)(ws + 8 * MB);
    f16* Kh = (f16*)(ws + 16 * MB);
    f16* VT = (f16*)(ws + 24 * MB);
    float* sx = (float*)(ws + 32 * MB);
    float* rq = (float*)(ws + 32 * MB + 16 * KB);
    float* rk = (float*)(ws + 32 * MB + 32 * KB);
    float* Mp = (float*)(ws + 32 * MB + 48 * KB);    // [4096][16]
    float* Lp = (float*)(ws + 32 * MB + 304 * KB);   // [4096][16]
    f16* Pu = (f16*)(ws + 40 * MB);       // 32 MB, written by qkrank1
    // Dead-before-Pu region:
    f16* Xh  = (f16*)(ws + 40 * MB);
    f16* Xl  = (f16*)(ws + 48 * MB);
    f16* Wqh = (f16*)(ws + 56 * MB);
    f16* Wkh = (f16*)(ws + 58 * MB);
    f16* Wvh = (f16*)(ws + 60 * MB);

    // Zero output (pvstrip accumulates atomically) and rq/rk.
    hipMemsetAsync(O, 0, (size_t)SEQ * DIM * 4, stream);
    hipMemsetAsync(rq, 0, 32 * KB, stream);

    // Merged input split + weight transposes.
    prep<<<4096 + 3072, 256, 0, stream>>>(x, wq, wk, wv, Xh, Xl, sx,
                                          Wqh, Wkh, Wvh);

    // All three projections in one dispatch (sets: Q, K, V), 2-pass each;
    // Q/K row-sums fused via atomics; K's lo plane not materialized.
    gemm128s<2, 16><<<dim3(32, 24), 256, 0, stream>>>(
        Xh, Xl, DIM, DIM,
        Wqh, Wqh, Qh, Ql,
        Wkh, Wkh, Kh, nullptr,
        Wvh, Wvh, VT, nullptr,
        rq, rk,
        EPI_SPLIT16, EPI_SPLIT16, EPI_TRANS16,
        DIM, 1.f);

    // Pu = exp(S - m_b) per 256-col strip + (m_b, l_b) partials.
    qkrank1<2, 16><<<256, 512, 0, stream>>>(
        Qh, Kh, Ql, Kh, sx, rq, rk, Pu, Mp, Lp);

    // O += sum_strips D * (Pu @ V), split-K x2, in-kernel D, atomic output.
    pvstrip<32><<<dim3(32, 16), 256, 0, stream>>>(Pu, VT, Mp, Lp, O);
}

// Round 14
// 224.654 us; speedup vs baseline: 1.0566x; 1.0566x over previous
//
#include <hip/hip_runtime.h>
#include <math.h>

#define SEQ 4096
#define DIM 1024

typedef _Float16 f16;
typedef _Float16 f16x8 __attribute__((ext_vector_type(8)));
typedef _Float16 f16x4 __attribute__((ext_vector_type(4)));
typedef float f32x4 __attribute__((ext_vector_type(4)));

#define GLOAD_LDS16(g, l)                                              \
    __builtin_amdgcn_global_load_lds(                                  \
        (const __attribute__((address_space(1))) void*)(g),            \
        (__attribute__((address_space(3))) void*)(l), 16, 0, 0)

// ---------------------------------------------------------------------------
// Split f32 -> (hi, lo) fp16 + per-row sum.  One block == one row (DIM=1024).
// ---------------------------------------------------------------------------
__global__ __launch_bounds__(256) void split16rs(const float* __restrict__ in,
                                                 f16* __restrict__ hi,
                                                 f16* __restrict__ lo,
                                                 float* __restrict__ sx) {
    __shared__ float sred[4];
    const int tid = threadIdx.x;
    const int i = blockIdx.x * 256 + tid;
    const float4 v = ((const float4*)in)[i];
    const float vv[4] = {v.x, v.y, v.z, v.w};
    f16x4 h, l;
#pragma unroll
    for (int q = 0; q < 4; ++q) {
        const f16 hq = (f16)vv[q];
        h[q] = hq;
        l[q] = (f16)(vv[q] - (float)hq);
    }
    ((f16x4*)hi)[i] = h;
    ((f16x4*)lo)[i] = l;
    float s = v.x + v.y + v.z + v.w;
#pragma unroll
    for (int m = 32; m >= 1; m >>= 1) s += __shfl_xor(s, m);
    if ((tid & 63) == 0) sred[tid >> 6] = s;
    __syncthreads();
    if (tid == 0) sx[blockIdx.x] = sred[0] + sred[1] + sred[2] + sred[3];
}

// ---------------------------------------------------------------------------
// Transpose-convert weights -> W^T fp16.  z=0: wq-0.5, z=1: wk-0.5, z=2: wv.
// ---------------------------------------------------------------------------
__global__ __launch_bounds__(256) void wtrans3h(
    const float* __restrict__ Wq, const float* __restrict__ Wk,
    const float* __restrict__ Wv,
    f16* __restrict__ QT, f16* __restrict__ KT, f16* __restrict__ VT) {
    __shared__ float tile[32][33];
    const int tid = threadIdx.x;
    const int r0 = blockIdx.x * 32;  // W row (k)
    const int c0 = blockIdx.y * 32;  // W col (n)
    const int z = blockIdx.z;
    const float* W = (z == 0) ? Wq : (z == 1) ? Wk : Wv;
    f16* T = (z == 0) ? QT : (z == 1) ? KT : VT;
    const float off = (z < 2) ? 0.5f : 0.0f;
    {
        const int r = tid >> 3, c = (tid & 7) * 4;
        const float4 v = *(const float4*)&W[(size_t)(r0 + r) * DIM + c0 + c];
        tile[r][c + 0] = v.x;
        tile[r][c + 1] = v.y;
        tile[r][c + 2] = v.z;
        tile[r][c + 3] = v.w;
    }
    __syncthreads();
    {
        const int n = tid >> 3;
        const int k = (tid & 7) * 4;
        f16x4 h;
#pragma unroll
        for (int q = 0; q < 4; ++q) h[q] = (f16)(tile[k + q][n] - off);
        *(f16x4*)&T[(size_t)(c0 + n) * DIM + r0 + k] = h;
    }
}

// ---------------------------------------------------------------------------
// Generalized 128x128 fp16 MFMA GEMM (proven schedule): BK=64, 256 thr,
// double-buffered counted-vmcnt, XOR swizzle, XCD swizzle.  3 sets by by>>3.
// EPI_SPLIT16 additionally: fused per-row sum -> atomicAdd into rs (if set).
// ---------------------------------------------------------------------------
#define EPI_F32 0
#define EPI_SPLIT16 1
#define EPI_TRANS16 2

template <int NPAIR, int KTILES>
__global__ __launch_bounds__(256, 2) void gemm128s(
    const f16* __restrict__ A0, const f16* __restrict__ A1, int ldA, int ldB,
    const f16* __restrict__ B0_0, const f16* __restrict__ B1_0,
    void* o0_0, void* o1_0,
    const f16* __restrict__ B0_1, const f16* __restrict__ B1_1,
    void* o0_1, void* o1_1,
    const f16* __restrict__ B0_2, const f16* __restrict__ B1_2,
    void* o0_2, void* o1_2,
    float* rs0, float* rs1,
    int epi0, int epi1, int epi2,
    int N, float scale) {
    __shared__ __align__(16) f16 As[2][128 * 64];
    __shared__ __align__(16) f16 Bs[2][128 * 64];

    const int tid = threadIdx.x;
    const int lane = tid & 63;
    const int wid = tid >> 6;
    const int wr = wid >> 1, wc = wid & 1;

    const int total = (int)(gridDim.y << 5);
    int lid = (int)blockIdx.y * 32 + (int)blockIdx.x;
    lid = (lid & 7) * (total >> 3) + (lid >> 3);
    const int bx = lid & 31;
    int by = lid >> 5;

    const int set = by >> 3;
    by &= 7;

    const f16 *B0, *B1;
    void *o0, *o1;
    int epi;
    float* rs;
    if (set == 0)      { B0 = B0_0; B1 = B1_0; o0 = o0_0; o1 = o1_0; epi = epi0; rs = rs0; }
    else if (set == 1) { B0 = B0_1; B1 = B1_1; o0 = o0_1; o1 = o1_1; epi = epi1; rs = rs1; }
    else               { B0 = B0_2; B1 = B1_2; o0 = o0_2; o1 = o1_2; epi = epi2; rs = nullptr; }

    const int m0 = bx * 128;
    const int n0 = by * 128;

    const f16* APs[2] = {A0, A1};
    const f16* BPs[2] = {B0, B1};
    const int nt = NPAIR * KTILES;

    f32x4 acc[4][4];
#pragma unroll
    for (int i = 0; i < 4; ++i)
#pragma unroll
        for (int j = 0; j < 4; ++j) acc[i][j] = (f32x4){0.f, 0.f, 0.f, 0.f};

    auto STAGE = [&](int t, int b) {
        const int pass = t / KTILES;
        const int k0 = (t % KTILES) * 64;
        const f16* Ap = APs[pass];
        const f16* Bp = BPs[pass];
#pragma unroll
        for (int L = 0; L < 4; ++L) {
            const int idx = L * 256 + tid;
            const int row = idx >> 3;
            const int sc = ((idx & 7) * 16) ^ ((row & 7) << 4);
            const int ldsu = (L * 256 + (tid & ~63)) * 8;
            GLOAD_LDS16(Ap + (size_t)(m0 + row) * ldA + k0 + (sc >> 1),
                        &As[b][ldsu]);
            GLOAD_LDS16(Bp + (size_t)(n0 + row) * ldB + k0 + (sc >> 1),
                        &Bs[b][ldsu]);
        }
    };

    STAGE(0, 0);

    for (int t = 0; t < nt; ++t) {
        const int cur = t & 1;
        __builtin_amdgcn_s_barrier();
        asm volatile("" ::: "memory");
        if (t + 1 < nt) {
            STAGE(t + 1, cur ^ 1);
            asm volatile("s_waitcnt vmcnt(8)" ::: "memory");
        } else {
            asm volatile("s_waitcnt vmcnt(0)" ::: "memory");
        }
        __builtin_amdgcn_s_barrier();
        asm volatile("" ::: "memory");

#pragma unroll
        for (int kk = 0; kk < 2; ++kk) {
            const int cb = kk * 64 + (lane >> 4) * 16;
            f16x8 af[4], bv[4];
#pragma unroll
            for (int i = 0; i < 4; ++i) {
                const int r = wr * 64 + i * 16 + (lane & 15);
                af[i] = *(const f16x8*)(&As[cur][r * 64 +
                                                 ((cb ^ ((r & 7) << 4)) >> 1)]);
            }
#pragma unroll
            for (int j = 0; j < 4; ++j) {
                const int r = wc * 64 + j * 16 + (lane & 15);
                bv[j] = *(const f16x8*)(&Bs[cur][r * 64 +
                                                 ((cb ^ ((r & 7) << 4)) >> 1)]);
            }
            __builtin_amdgcn_s_setprio(1);
#pragma unroll
            for (int i = 0; i < 4; ++i)
#pragma unroll
                for (int j = 0; j < 4; ++j)
                    acc[i][j] = __builtin_amdgcn_mfma_f32_16x16x32_f16(
                        af[i], bv[j], acc[i][j], 0, 0, 0);
            __builtin_amdgcn_s_setprio(0);
        }
    }

    const int row0 = m0 + wr * 64 + (lane >> 4) * 4;
    const int col0 = n0 + wc * 64 + (lane & 15);

    if (epi == EPI_F32) {
        float* O = (float*)o0;
#pragma unroll
        for (int i = 0; i < 4; ++i)
#pragma unroll
            for (int j = 0; j < 4; ++j)
#pragma unroll
                for (int q = 0; q < 4; ++q)
                    O[(size_t)(row0 + i * 16 + q) * N + col0 + j * 16] =
                        acc[i][j][q] * scale;
    } else if (epi == EPI_SPLIT16) {
        f16* Hi = (f16*)o0;
        f16* Lo = (f16*)o1;
#pragma unroll
        for (int i = 0; i < 4; ++i)
#pragma unroll
            for (int j = 0; j < 4; ++j)
#pragma unroll
                for (int q = 0; q < 4; ++q) {
                    const float x = acc[i][j][q];
                    const f16 h = (f16)x;
                    const size_t idx = (size_t)(row0 + i * 16 + q) * N + col0 + j * 16;
                    Hi[idx] = h;
                    if (Lo) Lo[idx] = (f16)(x - (float)h);
                }
        // Fused row-sum: rsum over this thread's 4 cols, reduce over the 16
        // lanes sharing rows (l15 group), one atomicAdd per row per wave.
        if (rs) {
#pragma unroll
            for (int i = 0; i < 4; ++i)
#pragma unroll
                for (int q = 0; q < 4; ++q) {
                    float rsum = acc[i][0][q] + acc[i][1][q] +
                                 acc[i][2][q] + acc[i][3][q];
#pragma unroll
                    for (int msk = 1; msk < 16; msk <<= 1)
                        rsum += __shfl_xor(rsum, msk);
                    if ((lane & 15) == 0)
                        atomicAdd(&rs[row0 + i * 16 + q], rsum);
                }
        }
    } else {  // EPI_TRANS16: out[col][row] over SEQ rows
        f16* OT = (f16*)o0;
#pragma unroll
        for (int i = 0; i < 4; ++i)
#pragma unroll
            for (int j = 0; j < 4; ++j) {
                f16x4 v;
#pragma unroll
                for (int q = 0; q < 4; ++q) v[q] = (f16)acc[i][j][q];
                *(f16x4*)&OT[(size_t)(col0 + j * 16) * SEQ + row0 + i * 16] = v;
            }
    }
}

// ---------------------------------------------------------------------------
// QK~ 256x256 fp16 GEMM + rank-1 epilogue + block-local softmax (round 10).
// ---------------------------------------------------------------------------
template <int NPAIR, int KT>
__global__ __launch_bounds__(512, 2) void qkrank1(
    const f16* __restrict__ A0, const f16* __restrict__ B0,
    const f16* __restrict__ A1, const f16* __restrict__ B1,
    const float* __restrict__ sx, const float* __restrict__ rq,
    const float* __restrict__ rk,
    f16* __restrict__ Pu, float* __restrict__ Mp, float* __restrict__ Lp) {
    constexpr int K = KT * 64;
    constexpr int nt = NPAIR * KT;
    __shared__ __align__(16) f16 As[2][256 * 64];   // 64 KB
    __shared__ __align__(16) f16 Bs[2][256 * 64];   // 64 KB

    const int tid = threadIdx.x;
    const int lane = tid & 63;
    const int wid = tid >> 6;
    const int wr = wid >> 2;
    const int wc = wid & 3;

    const int wg = ((int)blockIdx.x & 7) * 32 + ((int)blockIdx.x >> 3);
    const int m0 = (wg >> 4) * 256;
    const int n0 = (wg & 15) * 256;
    const int bcol = n0 >> 8;

    const f16* APs[2] = {A0, A1};
    const f16* BPs[2] = {B0, B1};

    f32x4 acc[8][4];
#pragma unroll
    for (int i = 0; i < 8; ++i)
#pragma unroll
        for (int j = 0; j < 4; ++j) acc[i][j] = (f32x4){0.f, 0.f, 0.f, 0.f};

    auto STAGE = [&](int t, int b) {
        const f16* Ap = APs[t / KT];
        const f16* Bp = BPs[t / KT];
        const int k0 = (t % KT) * 64;
#pragma unroll
        for (int L = 0; L < 4; ++L) {
            const int idx = L * 512 + tid;
            const int row = idx >> 3;
            const int sc = ((idx & 7) * 16) ^ ((row & 7) << 4);
            const int ldsu = (L * 512 + (tid & ~63)) * 8;
            GLOAD_LDS16(Ap + (size_t)(m0 + row) * K + k0 + (sc >> 1),
                        &As[b][ldsu]);
            GLOAD_LDS16(Bp + (size_t)(n0 + row) * K + k0 + (sc >> 1),
                        &Bs[b][ldsu]);
        }
    };

    STAGE(0, 0);

    for (int t = 0; t < nt; ++t) {
        const int cur = t & 1;
        __builtin_amdgcn_s_barrier();
        asm volatile("" ::: "memory");
        if (t + 1 < nt) {
            STAGE(t + 1, cur ^ 1);
            asm volatile("s_waitcnt vmcnt(8)" ::: "memory");
        } else {
            asm volatile("s_waitcnt vmcnt(0)" ::: "memory");
        }
        __builtin_amdgcn_s_barrier();
        asm volatile("" ::: "memory");

#pragma unroll
        for (int kk = 0; kk < 2; ++kk) {
            const int cb = kk * 64 + (lane >> 4) * 16;
            f16x8 af[8], bv[4];
#pragma unroll
            for (int i = 0; i < 8; ++i) {
                const int r = wr * 128 + i * 16 + (lane & 15);
                af[i] = *(const f16x8*)(&As[cur][r * 64 +
                                                 ((cb ^ ((r & 7) << 4)) >> 1)]);
            }
#pragma unroll
            for (int j = 0; j < 4; ++j) {
                const int r = wc * 64 + j * 16 + (lane & 15);
                bv[j] = *(const f16x8*)(&Bs[cur][r * 64 +
                                                 ((cb ^ ((r & 7) << 4)) >> 1)]);
            }
            __builtin_amdgcn_s_setprio(1);
#pragma unroll
            for (int i = 0; i < 8; ++i)
#pragma unroll
                for (int j = 0; j < 4; ++j)
                    acc[i][j] = __builtin_amdgcn_mfma_f32_16x16x32_f16(
                        af[i], bv[j], acc[i][j], 0, 0, 0);
            __builtin_amdgcn_s_setprio(0);
        }
    }

    // ---- epilogue: rank-1 + scale (in place) ----
    const int g4 = lane >> 4;
    const int l15 = lane & 15;
    const int row0 = m0 + wr * 128 + g4 * 4;   // + i*16 + q
    const int col0 = n0 + wc * 64 + l15;       // + j*16
    float u[4], w4[4];
#pragma unroll
    for (int j = 0; j < 4; ++j) {
        const float sxc = sx[col0 + j * 16];
        u[j] = 256.f * sxc + 0.5f * rk[col0 + j * 16];
        w4[j] = 0.5f * sxc;
    }
#pragma unroll
    for (int i = 0; i < 8; ++i)
#pragma unroll
        for (int q = 0; q < 4; ++q) {
            const int r = row0 + i * 16 + q;
            const float sxr = sx[r];
            const float rqr = rq[r];
#pragma unroll
            for (int j = 0; j < 4; ++j)
                acc[i][j][q] =
                    (acc[i][j][q] + sxr * u[j] + rqr * w4[j]) * 0.03125f;
        }

    // ---- block-local softmax over the 256-col strip ----
    float* partm = (float*)&As[0][0];      // [256][4]
    float* mrow  = partm + 1024;           // [256]
    float* parts = mrow + 256;             // [256][4]
    float red[8][4];
#pragma unroll
    for (int i = 0; i < 8; ++i)
#pragma unroll
        for (int q = 0; q < 4; ++q) {
            float v = acc[i][0][q];
#pragma unroll
            for (int j = 1; j < 4; ++j) v = fmaxf(v, acc[i][j][q]);
            red[i][q] = v;
        }
#pragma unroll
    for (int msk = 1; msk < 16; msk <<= 1)
#pragma unroll
        for (int i = 0; i < 8; ++i)
#pragma unroll
            for (int q = 0; q < 4; ++q)
                red[i][q] = fmaxf(red[i][q], __shfl_xor(red[i][q], msk));
    __syncthreads();
    if (l15 == 0)
#pragma unroll
        for (int i = 0; i < 8; ++i)
#pragma unroll
            for (int q = 0; q < 4; ++q)
                partm[(wr * 128 + i * 16 + g4 * 4 + q) * 4 + wc] = red[i][q];
    __syncthreads();
    if (tid < 256) {
        const float* p = partm + tid * 4;
        mrow[tid] = fmaxf(fmaxf(p[0], p[1]), fmaxf(p[2], p[3]));
    }
    __syncthreads();
#pragma unroll
    for (int i = 0; i < 8; ++i)
#pragma unroll
        for (int q = 0; q < 4; ++q) {
            const float mB = mrow[wr * 128 + i * 16 + g4 * 4 + q];
            float s = 0.f;
#pragma unroll
            for (int j = 0; j < 4; ++j) {
                const float e = __expf(acc[i][j][q] - mB);
                acc[i][j][q] = e;
                s += e;
            }
            red[i][q] = s;
        }
#pragma unroll
    for (int msk = 1; msk < 16; msk <<= 1)
#pragma unroll
        for (int i = 0; i < 8; ++i)
#pragma unroll
            for (int q = 0; q < 4; ++q) red[i][q] += __shfl_xor(red[i][q], msk);
    if (l15 == 0)
#pragma unroll
        for (int i = 0; i < 8; ++i)
#pragma unroll
            for (int q = 0; q < 4; ++q)
                parts[(wr * 128 + i * 16 + g4 * 4 + q) * 4 + wc] = red[i][q];
    __syncthreads();
    if (tid < 256) {
        const float* p = parts + tid * 4;
        Mp[(size_t)(m0 + tid) * 16 + bcol] = mrow[tid];
        Lp[(size_t)(m0 + tid) * 16 + bcol] = p[0] + p[1] + p[2] + p[3];
    }
    // ---- write Pu (f16, unnormalized exp) ----
#pragma unroll
    for (int i = 0; i < 8; ++i)
#pragma unroll
        for (int q = 0; q < 4; ++q) {
            const size_t r = row0 + i * 16 + q;
#pragma unroll
            for (int j = 0; j < 4; ++j)
                Pu[r * SEQ + col0 + j * 16] = (f16)acc[i][j][q];
        }
}

// ---------------------------------------------------------------------------
// mkD: D[r][b] = exp(m_b - m) / l  (one thread per row).
// ---------------------------------------------------------------------------
__global__ __launch_bounds__(256) void mkD(const float* __restrict__ Mp,
                                           const float* __restrict__ Lp,
                                           float* __restrict__ D) {
    const size_t r = blockIdx.x * 256 + threadIdx.x;
    float mv[16], lv[16];
#pragma unroll
    for (int b = 0; b < 16; ++b) mv[b] = Mp[r * 16 + b];
#pragma unroll
    for (int b = 0; b < 16; ++b) lv[b] = Lp[r * 16 + b];
    float m = mv[0];
#pragma unroll
    for (int b = 1; b < 16; ++b) m = fmaxf(m, mv[b]);
    float l = 0.f;
#pragma unroll
    for (int b = 0; b < 16; ++b) l += __expf(mv[b] - m) * lv[b];
    const float inv = 1.f / l;
#pragma unroll
    for (int b = 0; b < 16; ++b) D[r * 16 + b] = __expf(mv[b] - m) * inv;
}

// ---------------------------------------------------------------------------
// PV with folded normalization: O_half = sum_strips D[r][strip] * (Pu @ VT).
// Proven 128x128 schedule; strip (256 k) = 4 BK-tiles; at each strip end
// acc2 += D*acc, acc = 0.  Split-K x2 via sets (by>>3) -> P0 / P1.
// ---------------------------------------------------------------------------
template <int KTILES>   // tiles per K-half (32)
__global__ __launch_bounds__(256, 2) void pvstrip(
    const f16* __restrict__ Pu, const f16* __restrict__ VT,
    const float* __restrict__ D,
    float* __restrict__ P0, float* __restrict__ P1) {
    __shared__ __align__(16) f16 As[2][128 * 64];
    __shared__ __align__(16) f16 Bs[2][128 * 64];

    const int tid = threadIdx.x;
    const int lane = tid & 63;
    const int wid = tid >> 6;
    const int wr = wid >> 1, wc = wid & 1;

    const int total = (int)(gridDim.y << 5);
    int lid = (int)blockIdx.y * 32 + (int)blockIdx.x;
    lid = (lid & 7) * (total >> 3) + (lid >> 3);
    const int bx = lid & 31;
    int by = lid >> 5;
    const int set = by >> 3;
    by &= 7;
    float* Out = set ? P1 : P0;
    const int koff = set * 2048;           // element offset along K
    const int strip0 = set * 8;

    const int m0 = bx * 128;
    const int n0 = by * 128;
    const int row0 = m0 + wr * 64 + (lane >> 4) * 4;
    const int col0 = n0 + wc * 64 + (lane & 15);

    f32x4 acc[4][4], acc2[4][4];
#pragma unroll
    for (int i = 0; i < 4; ++i)
#pragma unroll
        for (int j = 0; j < 4; ++j) {
            acc[i][j] = (f32x4){0.f, 0.f, 0.f, 0.f};
            acc2[i][j] = (f32x4){0.f, 0.f, 0.f, 0.f};
        }

    auto STAGE = [&](int t, int b) {
        const int k0 = t * 64 + koff;
#pragma unroll
        for (int L = 0; L < 4; ++L) {
            const int idx = L * 256 + tid;
            const int row = idx >> 3;
            const int sc = ((idx & 7) * 16) ^ ((row & 7) << 4);
            const int ldsu = (L * 256 + (tid & ~63)) * 8;
            GLOAD_LDS16(Pu + (size_t)(m0 + row) * SEQ + k0 + (sc >> 1),
                        &As[b][ldsu]);
            GLOAD_LDS16(VT + (size_t)(n0 + row) * SEQ + k0 + (sc >> 1),
                        &Bs[b][ldsu]);
        }
    };

    STAGE(0, 0);

    for (int t = 0; t < KTILES; ++t) {
        const int cur = t & 1;
        __builtin_amdgcn_s_barrier();
        asm volatile("" ::: "memory");
        if (t + 1 < KTILES) {
            STAGE(t + 1, cur ^ 1);
            asm volatile("s_waitcnt vmcnt(8)" ::: "memory");
        } else {
            asm volatile("s_waitcnt vmcnt(0)" ::: "memory");
        }
        __builtin_amdgcn_s_barrier();
        asm volatile("" ::: "memory");

#pragma unroll
        for (int kk = 0; kk < 2; ++kk) {
            const int cb = kk * 64 + (lane >> 4) * 16;
            f16x8 af[4], bv[4];
#pragma unroll
            for (int i = 0; i < 4; ++i) {
                const int r = wr * 64 + i * 16 + (lane & 15);
                af[i] = *(const f16x8*)(&As[cur][r * 64 +
                                                 ((cb ^ ((r & 7) << 4)) >> 1)]);
            }
#pragma unroll
            for (int j = 0; j < 4; ++j) {
                const int r = wc * 64 + j * 16 + (lane & 15);
                bv[j] = *(const f16x8*)(&Bs[cur][r * 64 +
                                                 ((cb ^ ((r & 7) << 4)) >> 1)]);
            }
            __builtin_amdgcn_s_setprio(1);
#pragma unroll
            for (int i = 0; i < 4; ++i)
#pragma unroll
                for (int j = 0; j < 4; ++j)
                    acc[i][j] = __builtin_amdgcn_mfma_f32_16x16x32_f16(
                        af[i], bv[j], acc[i][j], 0, 0, 0);
            __builtin_amdgcn_s_setprio(0);
        }

        if ((t & 3) == 3) {   // strip boundary: fold D and reset partial
            const int strip = strip0 + (t >> 2);
#pragma unroll
            for (int i = 0; i < 4; ++i)
#pragma unroll
                for (int q = 0; q < 4; ++q) {
                    const float dv = D[(size_t)(row0 + i * 16 + q) * 16 + strip];
#pragma unroll
                    for (int j = 0; j < 4; ++j) {
                        acc2[i][j][q] += dv * acc[i][j][q];
                        acc[i][j][q] = 0.f;
                    }
                }
        }
    }

#pragma unroll
    for (int i = 0; i < 4; ++i)
#pragma unroll
        for (int j = 0; j < 4; ++j)
#pragma unroll
            for (int q = 0; q < 4; ++q)
                Out[(size_t)(row0 + i * 16 + q) * DIM + col0 + j * 16] =
                    acc2[i][j][q];
}

// ---------------------------------------------------------------------------
// addf: O = P0 + P1 (f32), vectorized by 4.
// ---------------------------------------------------------------------------
__global__ __launch_bounds__(256) void addf(const float* __restrict__ a,
                                            const float* __restrict__ b,
                                            float* __restrict__ o) {
    const int i = blockIdx.x * 256 + threadIdx.x;
    const float4 x = ((const float4*)a)[i];
    const float4 y = ((const float4*)b)[i];
    ((float4*)o)[i] = make_float4(x.x + y.x, x.y + y.y, x.z + y.z, x.w + y.w);
}

// ---------------------------------------------------------------------------
extern "C" void kernel_launch(void* const* d_in, const int* in_sizes, int n_in,
                              void* d_out, int out_size, void* d_ws, size_t ws_size,
                              hipStream_t stream) {
    const float* x  = (const float*)d_in[0];
    const float* wq = (const float*)d_in[1];
    const float* wk = (const float*)d_in[2];
    const float* wv = (const float*)d_in[3];
    float* O = (float*)d_out;

    char* ws = (char*)d_ws;
    const size_t MB = 1024 * 1024;
    const size_t KB = 1024;
    f16* Qh = (f16*)(ws + 0 * MB);        // live: proj -> qk
    f16* Ql = (f16*)(ws + 8 * MB);
    f16* Kh = (f16*)(ws + 16 * MB);
    f16* VT = (f16*)(ws + 24 * MB);       // live: vproj -> pv
    float* sx = (float*)(ws + 32 * MB);
    float* rq = (float*)(ws + 32 * MB + 16 * KB);
    float* rk = (float*)(ws + 32 * MB + 32 * KB);
    float* Mp = (float*)(ws + 32 * MB + 48 * KB);    // [4096][16]
    float* Lp = (float*)(ws + 32 * MB + 304 * KB);   // [4096][16]
    float* D  = (float*)(ws + 33 * MB);              // [4096][16]
    f16* Pu = (f16*)(ws + 40 * MB);       // 32 MB, written by qkrank1
    float* P0 = (float*)(ws + 72 * MB);   // 16 MB PV partial (K half 0)
    float* P1 = (float*)(ws + 88 * MB);   // 16 MB PV partial (K half 1)
    // Dead-before-Pu region (all consumed before qkrank1 writes):
    f16* Xh  = (f16*)(ws + 40 * MB);
    f16* Xl  = (f16*)(ws + 48 * MB);
    f16* Wqh = (f16*)(ws + 56 * MB);
    f16* Wkh = (f16*)(ws + 58 * MB);
    f16* Wvh = (f16*)(ws + 60 * MB);

    split16rs<<<4096, 256, 0, stream>>>(x, Xh, Xl, sx);
    wtrans3h<<<dim3(DIM / 32, DIM / 32, 3), 256, 0, stream>>>(
        wq, wk, wv, Wqh, Wkh, Wvh);

    // Zero rq/rk for the fused atomic row-sums.
    hipMemsetAsync(rq, 0, 32 * KB, stream);

    // All three projections in one dispatch (sets: Q, K, V), 2-pass each;
    // Q/K row-sums fused via atomics; K's lo plane not materialized.
    gemm128s<2, 16><<<dim3(32, 24), 256, 0, stream>>>(
        Xh, Xl, DIM, DIM,
        Wqh, Wqh, Qh, Ql,
        Wkh, Wkh, Kh, nullptr,
        Wvh, Wvh, VT, nullptr,
        rq, rk,
        EPI_SPLIT16, EPI_SPLIT16, EPI_TRANS16,
        DIM, 1.f);

    // Pu = exp(S - m_b) per 256-col strip + (m_b, l_b) partials.
    qkrank1<2, 16><<<256, 512, 0, stream>>>(
        Qh, Kh, Ql, Kh, sx, rq, rk, Pu, Mp, Lp);

    // D[r][b] = exp(m_b - m)/l.
    mkD<<<16, 256, 0, stream>>>(Mp, Lp, D);

    // O_half = sum_strips D * (Pu @ V), split-K x2.
    pvstrip<32><<<dim3(32, 16), 256, 0, stream>>>(Pu, VT, D, P0, P1);

    addf<<<4096, 256, 0, stream>>>(P0, P1, O);
}

// Round 15
// 224.625 us; speedup vs baseline: 1.0567x; 1.0001x over previous
//
#include <hip/hip_runtime.h>
#include <math.h>

#define SEQ 4096
#define DIM 1024

typedef _Float16 f16;
typedef _Float16 f16x8 __attribute__((ext_vector_type(8)));
typedef _Float16 f16x4 __attribute__((ext_vector_type(4)));
typedef float f32x4 __attribute__((ext_vector_type(4)));

#define GLOAD_LDS16(g, l)                                              \
    __builtin_amdgcn_global_load_lds(                                  \
        (const __attribute__((address_space(1))) void*)(g),            \
        (__attribute__((address_space(3))) void*)(l), 16, 0, 0)

// ---------------------------------------------------------------------------
// Split f32 -> (hi, lo) fp16 + per-row sum.  One block == one row (DIM=1024).
// ---------------------------------------------------------------------------
__global__ __launch_bounds__(256) void split16rs(const float* __restrict__ in,
                                                 f16* __restrict__ hi,
                                                 f16* __restrict__ lo,
                                                 float* __restrict__ sx) {
    __shared__ float sred[4];
    const int tid = threadIdx.x;
    const int i = blockIdx.x * 256 + tid;
    const float4 v = ((const float4*)in)[i];
    const float vv[4] = {v.x, v.y, v.z, v.w};
    f16x4 h, l;
#pragma unroll
    for (int q = 0; q < 4; ++q) {
        const f16 hq = (f16)vv[q];
        h[q] = hq;
        l[q] = (f16)(vv[q] - (float)hq);
    }
    ((f16x4*)hi)[i] = h;
    ((f16x4*)lo)[i] = l;
    float s = v.x + v.y + v.z + v.w;
#pragma unroll
    for (int m = 32; m >= 1; m >>= 1) s += __shfl_xor(s, m);
    if ((tid & 63) == 0) sred[tid >> 6] = s;
    __syncthreads();
    if (tid == 0) sx[blockIdx.x] = sred[0] + sred[1] + sred[2] + sred[3];
}

// ---------------------------------------------------------------------------
// Transpose-convert weights -> W^T fp16.  z=0: wq-0.5, z=1: wk-0.5, z=2: wv.
// ---------------------------------------------------------------------------
__global__ __launch_bounds__(256) void wtrans3h(
    const float* __restrict__ Wq, const float* __restrict__ Wk,
    const float* __restrict__ Wv,
    f16* __restrict__ QT, f16* __restrict__ KT, f16* __restrict__ VT) {
    __shared__ float tile[32][33];
    const int tid = threadIdx.x;
    const int r0 = blockIdx.x * 32;  // W row (k)
    const int c0 = blockIdx.y * 32;  // W col (n)
    const int z = blockIdx.z;
    const float* W = (z == 0) ? Wq : (z == 1) ? Wk : Wv;
    f16* T = (z == 0) ? QT : (z == 1) ? KT : VT;
    const float off = (z < 2) ? 0.5f : 0.0f;
    {
        const int r = tid >> 3, c = (tid & 7) * 4;
        const float4 v = *(const float4*)&W[(size_t)(r0 + r) * DIM + c0 + c];
        tile[r][c + 0] = v.x;
        tile[r][c + 1] = v.y;
        tile[r][c + 2] = v.z;
        tile[r][c + 3] = v.w;
    }
    __syncthreads();
    {
        const int n = tid >> 3;
        const int k = (tid & 7) * 4;
        f16x4 h;
#pragma unroll
        for (int q = 0; q < 4; ++q) h[q] = (f16)(tile[k + q][n] - off);
        *(f16x4*)&T[(size_t)(c0 + n) * DIM + r0 + k] = h;
    }
}

// ---------------------------------------------------------------------------
// Generalized 128x128 fp16 MFMA GEMM (proven schedule): BK=64, 256 thr,
// double-buffered counted-vmcnt, XOR swizzle, XCD swizzle.  3 sets by by>>3.
// EPI_SPLIT16 additionally: fused per-row sum -> atomicAdd into rs (if set).
// ---------------------------------------------------------------------------
#define EPI_F32 0
#define EPI_SPLIT16 1
#define EPI_TRANS16 2

template <int NPAIR, int KTILES>
__global__ __launch_bounds__(256, 2) void gemm128s(
    const f16* __restrict__ A0, const f16* __restrict__ A1, int ldA, int ldB,
    const f16* __restrict__ B0_0, const f16* __restrict__ B1_0,
    void* o0_0, void* o1_0,
    const f16* __restrict__ B0_1, const f16* __restrict__ B1_1,
    void* o0_1, void* o1_1,
    const f16* __restrict__ B0_2, const f16* __restrict__ B1_2,
    void* o0_2, void* o1_2,
    float* rs0, float* rs1,
    int epi0, int epi1, int epi2,
    int N, float scale) {
    __shared__ __align__(16) f16 As[2][128 * 64];
    __shared__ __align__(16) f16 Bs[2][128 * 64];

    const int tid = threadIdx.x;
    const int lane = tid & 63;
    const int wid = tid >> 6;
    const int wr = wid >> 1, wc = wid & 1;

    const int total = (int)(gridDim.y << 5);
    int lid = (int)blockIdx.y * 32 + (int)blockIdx.x;
    lid = (lid & 7) * (total >> 3) + (lid >> 3);
    const int bx = lid & 31;
    int by = lid >> 5;

    const int set = by >> 3;
    by &= 7;

    const f16 *B0, *B1;
    void *o0, *o1;
    int epi;
    float* rs;
    if (set == 0)      { B0 = B0_0; B1 = B1_0; o0 = o0_0; o1 = o1_0; epi = epi0; rs = rs0; }
    else if (set == 1) { B0 = B0_1; B1 = B1_1; o0 = o0_1; o1 = o1_1; epi = epi1; rs = rs1; }
    else               { B0 = B0_2; B1 = B1_2; o0 = o0_2; o1 = o1_2; epi = epi2; rs = nullptr; }

    const int m0 = bx * 128;
    const int n0 = by * 128;

    const f16* APs[2] = {A0, A1};
    const f16* BPs[2] = {B0, B1};
    const int nt = NPAIR * KTILES;

    f32x4 acc[4][4];
#pragma unroll
    for (int i = 0; i < 4; ++i)
#pragma unroll
        for (int j = 0; j < 4; ++j) acc[i][j] = (f32x4){0.f, 0.f, 0.f, 0.f};

    auto STAGE = [&](int t, int b) {
        const int pass = t / KTILES;
        const int k0 = (t % KTILES) * 64;
        const f16* Ap = APs[pass];
        const f16* Bp = BPs[pass];
#pragma unroll
        for (int L = 0; L < 4; ++L) {
            const int idx = L * 256 + tid;
            const int row = idx >> 3;
            const int sc = ((idx & 7) * 16) ^ ((row & 7) << 4);
            const int ldsu = (L * 256 + (tid & ~63)) * 8;
            GLOAD_LDS16(Ap + (size_t)(m0 + row) * ldA + k0 + (sc >> 1),
                        &As[b][ldsu]);
            GLOAD_LDS16(Bp + (size_t)(n0 + row) * ldB + k0 + (sc >> 1),
                        &Bs[b][ldsu]);
        }
    };

    STAGE(0, 0);

    for (int t = 0; t < nt; ++t) {
        const int cur = t & 1;
        __builtin_amdgcn_s_barrier();
        asm volatile("" ::: "memory");
        if (t + 1 < nt) {
            STAGE(t + 1, cur ^ 1);
            asm volatile("s_waitcnt vmcnt(8)" ::: "memory");
        } else {
            asm volatile("s_waitcnt vmcnt(0)" ::: "memory");
        }
        __builtin_amdgcn_s_barrier();
        asm volatile("" ::: "memory");

#pragma unroll
        for (int kk = 0; kk < 2; ++kk) {
            const int cb = kk * 64 + (lane >> 4) * 16;
            f16x8 af[4], bv[4];
#pragma unroll
            for (int i = 0; i < 4; ++i) {
                const int r = wr * 64 + i * 16 + (lane & 15);
                af[i] = *(const f16x8*)(&As[cur][r * 64 +
                                                 ((cb ^ ((r & 7) << 4)) >> 1)]);
            }
#pragma unroll
            for (int j = 0; j < 4; ++j) {
                const int r = wc * 64 + j * 16 + (lane & 15);
                bv[j] = *(const f16x8*)(&Bs[cur][r * 64 +
                                                 ((cb ^ ((r & 7) << 4)) >> 1)]);
            }
            __builtin_amdgcn_s_setprio(1);
#pragma unroll
            for (int i = 0; i < 4; ++i)
#pragma unroll
                for (int j = 0; j < 4; ++j)
                    acc[i][j] = __builtin_amdgcn_mfma_f32_16x16x32_f16(
                        af[i], bv[j], acc[i][j], 0, 0, 0);
            __builtin_amdgcn_s_setprio(0);
        }
    }

    const int row0 = m0 + wr * 64 + (lane >> 4) * 4;
    const int col0 = n0 + wc * 64 + (lane & 15);

    if (epi == EPI_F32) {
        float* O = (float*)o0;
#pragma unroll
        for (int i = 0; i < 4; ++i)
#pragma unroll
            for (int j = 0; j < 4; ++j)
#pragma unroll
                for (int q = 0; q < 4; ++q)
                    O[(size_t)(row0 + i * 16 + q) * N + col0 + j * 16] =
                        acc[i][j][q] * scale;
    } else if (epi == EPI_SPLIT16) {
        f16* Hi = (f16*)o0;
        f16* Lo = (f16*)o1;
#pragma unroll
        for (int i = 0; i < 4; ++i)
#pragma unroll
            for (int j = 0; j < 4; ++j)
#pragma unroll
                for (int q = 0; q < 4; ++q) {
                    const float x = acc[i][j][q];
                    const f16 h = (f16)x;
                    const size_t idx = (size_t)(row0 + i * 16 + q) * N + col0 + j * 16;
                    Hi[idx] = h;
                    if (Lo) Lo[idx] = (f16)(x - (float)h);
                }
        // Fused row-sum: rsum over this thread's 4 cols, reduce over the 16
        // lanes sharing rows (l15 group), one atomicAdd per row per wave.
        if (rs) {
#pragma unroll
            for (int i = 0; i < 4; ++i)
#pragma unroll
                for (int q = 0; q < 4; ++q) {
                    float rsum = acc[i][0][q] + acc[i][1][q] +
                                 acc[i][2][q] + acc[i][3][q];
#pragma unroll
                    for (int msk = 1; msk < 16; msk <<= 1)
                        rsum += __shfl_xor(rsum, msk);
                    if ((lane & 15) == 0)
                        atomicAdd(&rs[row0 + i * 16 + q], rsum);
                }
        }
    } else {  // EPI_TRANS16: out[col][row] over SEQ rows
        f16* OT = (f16*)o0;
#pragma unroll
        for (int i = 0; i < 4; ++i)
#pragma unroll
            for (int j = 0; j < 4; ++j) {
                f16x4 v;
#pragma unroll
                for (int q = 0; q < 4; ++q) v[q] = (f16)acc[i][j][q];
                *(f16x4*)&OT[(size_t)(col0 + j * 16) * SEQ + row0 + i * 16] = v;
            }
    }
}

// ---------------------------------------------------------------------------
// QK~ 256x256 fp16 GEMM + rank-1 epilogue + block-local softmax.
// Tile->block mapping: L2-quadrant swizzle.  Each XCD's 32 concurrent
// blocks (1 blk/CU) cover a 4 m-tile x 8 n-tile rectangle, so the per-XCD
// staging working set (1 MB A + 2 MB B per pass) fits the 4 MB L2 and each
// panel is reused 8x/4x from L2 instead of refetched from L3.  Bijective.
// ---------------------------------------------------------------------------
template <int NPAIR, int KT>
__global__ __launch_bounds__(512, 2) void qkrank1(
    const f16* __restrict__ A0, const f16* __restrict__ B0,
    const f16* __restrict__ A1, const f16* __restrict__ B1,
    const float* __restrict__ sx, const float* __restrict__ rq,
    const float* __restrict__ rk,
    f16* __restrict__ Pu, float* __restrict__ Mp, float* __restrict__ Lp) {
    constexpr int K = KT * 64;
    constexpr int nt = NPAIR * KT;
    __shared__ __align__(16) f16 As[2][256 * 64];   // 64 KB
    __shared__ __align__(16) f16 Bs[2][256 * 64];   // 64 KB

    const int tid = threadIdx.x;
    const int lane = tid & 63;
    const int wid = tid >> 6;
    const int wr = wid >> 2;
    const int wc = wid & 3;

    // XCD swizzle (32 consecutive lids per XCD) + quadrant tile mapping.
    const int wg = ((int)blockIdx.x & 7) * 32 + ((int)blockIdx.x >> 3);
    const int quad = wg >> 4;          // 0..15: which 4x4 quadrant
    const int pos = wg & 15;           // position inside quadrant
    const int mt = (quad >> 2) * 4 + (pos >> 2);
    const int ntile = (quad & 3) * 4 + (pos & 3);
    const int m0 = mt * 256;
    const int n0 = ntile * 256;
    const int bcol = n0 >> 8;

    const f16* APs[2] = {A0, A1};
    const f16* BPs[2] = {B0, B1};

    f32x4 acc[8][4];
#pragma unroll
    for (int i = 0; i < 8; ++i)
#pragma unroll
        for (int j = 0; j < 4; ++j) acc[i][j] = (f32x4){0.f, 0.f, 0.f, 0.f};

    auto STAGE = [&](int t, int b) {
        const f16* Ap = APs[t / KT];
        const f16* Bp = BPs[t / KT];
        const int k0 = (t % KT) * 64;
#pragma unroll
        for (int L = 0; L < 4; ++L) {
            const int idx = L * 512 + tid;
            const int row = idx >> 3;
            const int sc = ((idx & 7) * 16) ^ ((row & 7) << 4);
            const int ldsu = (L * 512 + (tid & ~63)) * 8;
            GLOAD_LDS16(Ap + (size_t)(m0 + row) * K + k0 + (sc >> 1),
                        &As[b][ldsu]);
            GLOAD_LDS16(Bp + (size_t)(n0 + row) * K + k0 + (sc >> 1),
                        &Bs[b][ldsu]);
        }
    };

    STAGE(0, 0);

    for (int t = 0; t < nt; ++t) {
        const int cur = t & 1;
        __builtin_amdgcn_s_barrier();
        asm volatile("" ::: "memory");
        if (t + 1 < nt) {
            STAGE(t + 1, cur ^ 1);
            asm volatile("s_waitcnt vmcnt(8)" ::: "memory");
        } else {
            asm volatile("s_waitcnt vmcnt(0)" ::: "memory");
        }
        __builtin_amdgcn_s_barrier();
        asm volatile("" ::: "memory");

#pragma unroll
        for (int kk = 0; kk < 2; ++kk) {
            const int cb = kk * 64 + (lane >> 4) * 16;
            f16x8 af[8], bv[4];
#pragma unroll
            for (int i = 0; i < 8; ++i) {
                const int r = wr * 128 + i * 16 + (lane & 15);
                af[i] = *(const f16x8*)(&As[cur][r * 64 +
                                                 ((cb ^ ((r & 7) << 4)) >> 1)]);
            }
#pragma unroll
            for (int j = 0; j < 4; ++j) {
                const int r = wc * 64 + j * 16 + (lane & 15);
                bv[j] = *(const f16x8*)(&Bs[cur][r * 64 +
                                                 ((cb ^ ((r & 7) << 4)) >> 1)]);
            }
            __builtin_amdgcn_s_setprio(1);
#pragma unroll
            for (int i = 0; i < 8; ++i)
#pragma unroll
                for (int j = 0; j < 4; ++j)
                    acc[i][j] = __builtin_amdgcn_mfma_f32_16x16x32_f16(
                        af[i], bv[j], acc[i][j], 0, 0, 0);
            __builtin_amdgcn_s_setprio(0);
        }
    }

    // ---- epilogue: rank-1 + scale (in place) ----
    const int g4 = lane >> 4;
    const int l15 = lane & 15;
    const int row0 = m0 + wr * 128 + g4 * 4;   // + i*16 + q
    const int col0 = n0 + wc * 64 + l15;       // + j*16
    float u[4], w4[4];
#pragma unroll
    for (int j = 0; j < 4; ++j) {
        const float sxc = sx[col0 + j * 16];
        u[j] = 256.f * sxc + 0.5f * rk[col0 + j * 16];
        w4[j] = 0.5f * sxc;
    }
#pragma unroll
    for (int i = 0; i < 8; ++i)
#pragma unroll
        for (int q = 0; q < 4; ++q) {
            const int r = row0 + i * 16 + q;
            const float sxr = sx[r];
            const float rqr = rq[r];
#pragma unroll
            for (int j = 0; j < 4; ++j)
                acc[i][j][q] =
                    (acc[i][j][q] + sxr * u[j] + rqr * w4[j]) * 0.03125f;
        }

    // ---- block-local softmax over the 256-col strip ----
    float* partm = (float*)&As[0][0];      // [256][4]
    float* mrow  = partm + 1024;           // [256]
    float* parts = mrow + 256;             // [256][4]
    float red[8][4];
#pragma unroll
    for (int i = 0; i < 8; ++i)
#pragma unroll
        for (int q = 0; q < 4; ++q) {
            float v = acc[i][0][q];
#pragma unroll
            for (int j = 1; j < 4; ++j) v = fmaxf(v, acc[i][j][q]);
            red[i][q] = v;
        }
#pragma unroll
    for (int msk = 1; msk < 16; msk <<= 1)
#pragma unroll
        for (int i = 0; i < 8; ++i)
#pragma unroll
            for (int q = 0; q < 4; ++q)
                red[i][q] = fmaxf(red[i][q], __shfl_xor(red[i][q], msk));
    __syncthreads();
    if (l15 == 0)
#pragma unroll
        for (int i = 0; i < 8; ++i)
#pragma unroll
            for (int q = 0; q < 4; ++q)
                partm[(wr * 128 + i * 16 + g4 * 4 + q) * 4 + wc] = red[i][q];
    __syncthreads();
    if (tid < 256) {
        const float* p = partm + tid * 4;
        mrow[tid] = fmaxf(fmaxf(p[0], p[1]), fmaxf(p[2], p[3]));
    }
    __syncthreads();
#pragma unroll
    for (int i = 0; i < 8; ++i)
#pragma unroll
        for (int q = 0; q < 4; ++q) {
            const float mB = mrow[wr * 128 + i * 16 + g4 * 4 + q];
            float s = 0.f;
#pragma unroll
            for (int j = 0; j < 4; ++j) {
                const float e = __expf(acc[i][j][q] - mB);
                acc[i][j][q] = e;
                s += e;
            }
            red[i][q] = s;
        }
#pragma unroll
    for (int msk = 1; msk < 16; msk <<= 1)
#pragma unroll
        for (int i = 0; i < 8; ++i)
#pragma unroll
            for (int q = 0; q < 4; ++q) red[i][q] += __shfl_xor(red[i][q], msk);
    if (l15 == 0)
#pragma unroll
        for (int i = 0; i < 8; ++i)
#pragma unroll
            for (int q = 0; q < 4; ++q)
                parts[(wr * 128 + i * 16 + g4 * 4 + q) * 4 + wc] = red[i][q];
    __syncthreads();
    if (tid < 256) {
        const float* p = parts + tid * 4;
        Mp[(size_t)(m0 + tid) * 16 + bcol] = mrow[tid];
        Lp[(size_t)(m0 + tid) * 16 + bcol] = p[0] + p[1] + p[2] + p[3];
    }
    // ---- write Pu (f16, unnormalized exp) ----
#pragma unroll
    for (int i = 0; i < 8; ++i)
#pragma unroll
        for (int q = 0; q < 4; ++q) {
            const size_t r = row0 + i * 16 + q;
#pragma unroll
            for (int j = 0; j < 4; ++j)
                Pu[r * SEQ + col0 + j * 16] = (f16)acc[i][j][q];
        }
}

// ---------------------------------------------------------------------------
// mkD: D[r][b] = exp(m_b - m) / l  (one thread per row).
// ---------------------------------------------------------------------------
__global__ __launch_bounds__(256) void mkD(const float* __restrict__ Mp,
                                           const float* __restrict__ Lp,
                                           float* __restrict__ D) {
    const size_t r = blockIdx.x * 256 + threadIdx.x;
    float mv[16], lv[16];
#pragma unroll
    for (int b = 0; b < 16; ++b) mv[b] = Mp[r * 16 + b];
#pragma unroll
    for (int b = 0; b < 16; ++b) lv[b] = Lp[r * 16 + b];
    float m = mv[0];
#pragma unroll
    for (int b = 1; b < 16; ++b) m = fmaxf(m, mv[b]);
    float l = 0.f;
#pragma unroll
    for (int b = 0; b < 16; ++b) l += __expf(mv[b] - m) * lv[b];
    const float inv = 1.f / l;
#pragma unroll
    for (int b = 0; b < 16; ++b) D[r * 16 + b] = __expf(mv[b] - m) * inv;
}

// ---------------------------------------------------------------------------
// PV with folded normalization: O_half = sum_strips D[r][strip] * (Pu @ VT).
// Proven 128x128 schedule; strip (256 k) = 4 BK-tiles; at each strip end
// acc2 += D*acc, acc = 0.  Split-K x2 via sets (by>>3) -> P0 / P1.
// ---------------------------------------------------------------------------
template <int KTILES>   // tiles per K-half (32)
__global__ __launch_bounds__(256, 2) void pvstrip(
    const f16* __restrict__ Pu, const f16* __restrict__ VT,
    const float* __restrict__ D,
    float* __restrict__ P0, float* __restrict__ P1) {
    __shared__ __align__(16) f16 As[2][128 * 64];
    __shared__ __align__(16) f16 Bs[2][128 * 64];

    const int tid = threadIdx.x;
    const int lane = tid & 63;
    const int wid = tid >> 6;
    const int wr = wid >> 1, wc = wid & 1;

    const int total = (int)(gridDim.y << 5);
    int lid = (int)blockIdx.y * 32 + (int)blockIdx.x;
    lid = (lid & 7) * (total >> 3) + (lid >> 3);
    const int bx = lid & 31;
    int by = lid >> 5;
    const int set = by >> 3;
    by &= 7;
    float* Out = set ? P1 : P0;
    const int koff = set * 2048;           // element offset along K
    const int strip0 = set * 8;

    const int m0 = bx * 128;
    const int n0 = by * 128;
    const int row0 = m0 + wr * 64 + (lane >> 4) * 4;
    const int col0 = n0 + wc * 64 + (lane & 15);

    f32x4 acc[4][4], acc2[4][4];
#pragma unroll
    for (int i = 0; i < 4; ++i)
#pragma unroll
        for (int j = 0; j < 4; ++j) {
            acc[i][j] = (f32x4){0.f, 0.f, 0.f, 0.f};
            acc2[i][j] = (f32x4){0.f, 0.f, 0.f, 0.f};
        }

    auto STAGE = [&](int t, int b) {
        const int k0 = t * 64 + koff;
#pragma unroll
        for (int L = 0; L < 4; ++L) {
            const int idx = L * 256 + tid;
            const int row = idx >> 3;
            const int sc = ((idx & 7) * 16) ^ ((row & 7) << 4);
            const int ldsu = (L * 256 + (tid & ~63)) * 8;
            GLOAD_LDS16(Pu + (size_t)(m0 + row) * SEQ + k0 + (sc >> 1),
                        &As[b][ldsu]);
            GLOAD_LDS16(VT + (size_t)(n0 + row) * SEQ + k0 + (sc >> 1),
                        &Bs[b][ldsu]);
        }
    };

    STAGE(0, 0);

    for (int t = 0; t < KTILES; ++t) {
        const int cur = t & 1;
        __builtin_amdgcn_s_barrier();
        asm volatile("" ::: "memory");
        if (t + 1 < KTILES) {
            STAGE(t + 1, cur ^ 1);
            asm volatile("s_waitcnt vmcnt(8)" ::: "memory");
        } else {
            asm volatile("s_waitcnt vmcnt(0)" ::: "memory");
        }
        __builtin_amdgcn_s_barrier();
        asm volatile("" ::: "memory");

#pragma unroll
        for (int kk = 0; kk < 2; ++kk) {
            const int cb = kk * 64 + (lane >> 4) * 16;
            f16x8 af[4], bv[4];
#pragma unroll
            for (int i = 0; i < 4; ++i) {
                const int r = wr * 64 + i * 16 + (lane & 15);
                af[i] = *(const f16x8*)(&As[cur][r * 64 +
                                                 ((cb ^ ((r & 7) << 4)) >> 1)]);
            }
#pragma unroll
            for (int j = 0; j < 4; ++j) {
                const int r = wc * 64 + j * 16 + (lane & 15);
                bv[j] = *(const f16x8*)(&Bs[cur][r * 64 +
                                                 ((cb ^ ((r & 7) << 4)) >> 1)]);
            }
            __builtin_amdgcn_s_setprio(1);
#pragma unroll
            for (int i = 0; i < 4; ++i)
#pragma unroll
                for (int j = 0; j < 4; ++j)
                    acc[i][j] = __builtin_amdgcn_mfma_f32_16x16x32_f16(
                        af[i], bv[j], acc[i][j], 0, 0, 0);
            __builtin_amdgcn_s_setprio(0);
        }

        if ((t & 3) == 3) {   // strip boundary: fold D and reset partial
            const int strip = strip0 + (t >> 2);
#pragma unroll
            for (int i = 0; i < 4; ++i)
#pragma unroll
                for (int q = 0; q < 4; ++q) {
                    const float dv = D[(size_t)(row0 + i * 16 + q) * 16 + strip];
#pragma unroll
                    for (int j = 0; j < 4; ++j) {
                        acc2[i][j][q] += dv * acc[i][j][q];
                        acc[i][j][q] = 0.f;
                    }
                }
        }
    }

#pragma unroll
    for (int i = 0; i < 4; ++i)
#pragma unroll
        for (int j = 0; j < 4; ++j)
#pragma unroll
            for (int q = 0; q < 4; ++q)
                Out[(size_t)(row0 + i * 16 + q) * DIM + col0 + j * 16] =
                    acc2[i][j][q];
}

// ---------------------------------------------------------------------------
// addf: O = P0 + P1 (f32), vectorized by 4.
// ---------------------------------------------------------------------------
__global__ __launch_bounds__(256) void addf(const float* __restrict__ a,
                                            const float* __restrict__ b,
                                            float* __restrict__ o) {
    const int i = blockIdx.x * 256 + threadIdx.x;
    const float4 x = ((const float4*)a)[i];
    const float4 y = ((const float4*)b)[i];
    ((float4*)o)[i] = make_float4(x.x + y.x, x.y + y.y, x.z + y.z, x.w + y.w);
}

// ---------------------------------------------------------------------------
extern "C" void kernel_launch(void* const* d_in, const int* in_sizes, int n_in,
                              void* d_out, int out_size, void* d_ws, size_t ws_size,
                              hipStream_t stream) {
    const float* x  = (const float*)d_in[0];
    const float* wq = (const float*)d_in[1];
    const float* wk = (const float*)d_in[2];
    const float* wv = (const float*)d_in[3];
    float* O = (float*)d_out;

    char* ws = (char*)d_ws;
    const size_t MB = 1024 * 1024;
    const size_t KB = 1024;
    f16* Qh = (f16*)(ws + 0 * MB);        // live: proj -> qk
    f16* Ql = (f16*)(ws + 8 * MB);
    f16* Kh = (f16*)(ws + 16 * MB);
    f16* VT = (f16*)(ws + 24 * MB);       // live: vproj -> pv
    float* sx = (float*)(ws + 32 * MB);
    float* rq = (float*)(ws + 32 * MB + 16 * KB);
    float* rk = (float*)(ws + 32 * MB + 32 * KB);
    float* Mp = (float*)(ws + 32 * MB + 48 * KB);    // [4096][16]
    float* Lp = (float*)(ws + 32 * MB + 304 * KB);   // [4096][16]
    float* D  = (float*)(ws + 33 * MB);              // [4096][16]
    f16* Pu = (f16*)(ws + 40 * MB);       // 32 MB, written by qkrank1
    float* P0 = (float*)(ws + 72 * MB);   // 16 MB PV partial (K half 0)
    float* P1 = (float*)(ws + 88 * MB);   // 16 MB PV partial (K half 1)
    // Dead-before-Pu region (all consumed before qkrank1 writes):
    f16* Xh  = (f16*)(ws + 40 * MB);
    f16* Xl  = (f16*)(ws + 48 * MB);
    f16* Wqh = (f16*)(ws + 56 * MB);
    f16* Wkh = (f16*)(ws + 58 * MB);
    f16* Wvh = (f16*)(ws + 60 * MB);

    split16rs<<<4096, 256, 0, stream>>>(x, Xh, Xl, sx);
    wtrans3h<<<dim3(DIM / 32, DIM / 32, 3), 256, 0, stream>>>(
        wq, wk, wv, Wqh, Wkh, Wvh);

    // Zero rq/rk for the fused atomic row-sums.
    hipMemsetAsync(rq, 0, 32 * KB, stream);

    // All three projections in one dispatch (sets: Q, K, V), 2-pass each;
    // Q/K row-sums fused via atomics; K's lo plane not materialized.
    gemm128s<2, 16><<<dim3(32, 24), 256, 0, stream>>>(
        Xh, Xl, DIM, DIM,
        Wqh, Wqh, Qh, Ql,
        Wkh, Wkh, Kh, nullptr,
        Wvh, Wvh, VT, nullptr,
        rq, rk,
        EPI_SPLIT16, EPI_SPLIT16, EPI_TRANS16,
        DIM, 1.f);

    // Pu = exp(S - m_b) per 256-col strip + (m_b, l_b) partials.
    qkrank1<2, 16><<<256, 512, 0, stream>>>(
        Qh, Kh, Ql, Kh, sx, rq, rk, Pu, Mp, Lp);

    // D[r][b] = exp(m_b - m)/l.
    mkD<<<16, 256, 0, stream>>>(Mp, Lp, D);

    // O_half = sum_strips D * (Pu @ V), split-K x2.
    pvstrip<32><<<dim3(32, 16), 256, 0, stream>>>(Pu, VT, D, P0, P1);

    addf<<<4096, 256, 0, stream>>>(P0, P1, O);
}